// Round 20
// baseline (131.684 us; speedup 1.0000x reference)
//
#include <hip/hip_runtime.h>
#include <math.h>

#define FDIM 64    // input feature dim
#define NPB  256   // nodes per bucket (bucket = dst >> 8)
#define CAP2B 3456 // entries per bucket segment (mean 3069, +7 sigma)
#define NBMAX 400
#define TILE2 2048
#define EPT2 8     // TILE2 / 256
#define PTILE 128  // nodes per k_proj block

// ---------------- helpers ----------------

__device__ inline unsigned short f2bf(float f) {
    unsigned int u = __float_as_uint(f);
    unsigned int r = (u + 0x7fffu + ((u >> 16) & 1u)) >> 16;  // RNE
    return (unsigned short)r;
}
__device__ inline float bf_lo(unsigned int v) { return __uint_as_float(v << 16); }
__device__ inline float bf_hi(unsigned int v) { return __uint_as_float(v & 0xffff0000u); }
__device__ inline unsigned int bfpack(float a, float b) {
    return (unsigned int)f2bf(a) | ((unsigned int)f2bf(b) << 16);
}

__global__ __launch_bounds__(256) void k_zero(int* __restrict__ p, int n) {
    int i = blockIdx.x * 256 + threadIdx.x;
    if (i < n) p[i] = 0;
}

// ---------------- direct binning: edges -> 391 buckets, one pass -----------

__global__ __launch_bounds__(256) void k_binD(const int* __restrict__ src,
                                              const int* __restrict__ dst,
                                              int* __restrict__ bcnt,
                                              unsigned int* __restrict__ bin2,
                                              int E, int NB) {
    __shared__ int hb[NBMAX];   // histogram, then global base
    __shared__ int hc[NBMAX];   // rank cursor
    int tid = threadIdx.x;
    int base = blockIdx.x * TILE2;
    for (int i = tid; i < NB; i += 256) { hb[i] = 0; hc[i] = 0; }
    __syncthreads();
    unsigned int ent[EPT2]; int bk[EPT2];
#pragma unroll
    for (int k = 0; k < EPT2; ++k) {
        int i = base + k * 256 + tid;
        if (i < E) {
            int s = src[i], d = dst[i];
            bk[k] = d >> 8;
            ent[k] = ((unsigned int)s << 8) | (unsigned int)(d & 255);
            atomicAdd(&hb[bk[k]], 1);
        } else bk[k] = -1;
    }
    __syncthreads();
    for (int i = tid; i < NB; i += 256) {
        int c = hb[i];
        hb[i] = (c > 0) ? atomicAdd(&bcnt[i], c) : 0;
    }
    __syncthreads();
#pragma unroll
    for (int k = 0; k < EPT2; ++k) if (bk[k] >= 0) {
        int b = bk[k];
        int pos = hb[b] + atomicAdd(&hc[b], 1);
        if (pos < CAP2B) bin2[(size_t)b * CAP2B + pos] = ent[k];
    }
}

// ---------------- bucket-count scan -> CSR bases ----------------

__global__ __launch_bounds__(512) void k_bscan(const int* __restrict__ bcnt,
                                               int* __restrict__ cbase,
                                               int* __restrict__ row_ptr,
                                               int NB, int N, int T) {
    __shared__ int lds[512];
    int tid = threadIdx.x;
    int tot = 0;
    if (tid < NB)
        tot = min(bcnt[tid], CAP2B) + min(NPB, N - tid * NPB);  // + self entries
    lds[tid] = tot;
    __syncthreads();
    int val = tot;
#pragma unroll
    for (int off = 1; off < 512; off <<= 1) {
        int o = (tid >= off) ? lds[tid - off] : 0;
        __syncthreads();
        val += o;
        lds[tid] = val;
        __syncthreads();
    }
    if (tid < NB) cbase[tid] = val - tot;   // exclusive
    if (tid == 0) row_ptr[N] = T;
}

// per bucket: histogram (init 1 = self) + scan -> row_ptr/dinv, then scatter
// src-only CSR entries (weights folded into node scaling; see k_proj/hops)
__global__ __launch_bounds__(256) void k_build(const int* __restrict__ bcnt,
                                               const int* __restrict__ cbase,
                                               const unsigned int* __restrict__ bin2,
                                               int* __restrict__ row_ptr,
                                               float* __restrict__ dinv,
                                               int* __restrict__ csr_src, int N) {
    __shared__ int lcnt[256];
    __shared__ int lscan[256];
    __shared__ int lbase[256];
    __shared__ int lcur[256];
    int b = blockIdx.x, tid = threadIdx.x;
    int node = (b << 8) + tid;
    lcnt[tid] = (node < N) ? 1 : 0;          // self entry
    __syncthreads();
    int M = min(bcnt[b], CAP2B);
    const unsigned int* seg = bin2 + (size_t)b * CAP2B;
    for (int i = tid; i < M; i += 256)
        atomicAdd(&lcnt[seg[i] & 255u], 1);
    __syncthreads();
    int v = lcnt[tid];
    lscan[tid] = v;
    __syncthreads();
    int val = v;
#pragma unroll
    for (int off = 1; off < 256; off <<= 1) {
        int o = (tid >= off) ? lscan[tid - off] : 0;
        __syncthreads();
        val += o;
        lscan[tid] = val;
        __syncthreads();
    }
    int base = cbase[b] + (val - v);         // exclusive local offset
    if (node < N) {
        row_ptr[node] = base;
        dinv[node] = rsqrtf((float)v);       // count includes self entry
        csr_src[base] = node;                // self entry at slot 0
    }
    lbase[tid] = base;
    lcur[tid] = 1;                           // slot 0 taken by self
    __syncthreads();
    for (int i = tid; i < M; i += 256) {
        unsigned int en = seg[i];
        int dl = (int)(en & 255u);
        int pos = lbase[dl] + atomicAdd(&lcur[dl], 1);
        csr_src[pos] = (int)(en >> 8);
    }
}

// ---------------- projection -> split planes ----------------
// pA: [N][16 u32] = classes 0..31 (64B rows); pB: [N][4 u32] = classes 32..39

__global__ __launch_bounds__(256) void k_proj(const float* __restrict__ x,
                                              const float* __restrict__ W,
                                              const float* __restrict__ dinv,
                                              unsigned int* __restrict__ pA,
                                              unsigned int* __restrict__ pB,
                                              int N, int C) {
    __shared__ float xs[PTILE][65];
    __shared__ float Wl[40 * 65];
    int tid = threadIdx.x;
    int n0 = blockIdx.x * PTILE;

    for (int i = tid; i < 40 * 64; i += 256) {
        int c = i >> 6, f = i & 63;
        Wl[c * 65 + f] = W[i];
    }
    for (int idx = tid; idx < PTILE * 16; idx += 256) {
        int r = idx >> 4, c4 = (idx & 15) << 2;
        int n = n0 + r;
        float4 v = make_float4(0.f, 0.f, 0.f, 0.f);
        float dn = 0.f;
        if (n < N) {
            v = *(const float4*)&x[(size_t)n * FDIM + c4];
            dn = dinv[n];
        }
        xs[r][c4 + 0] = v.x * dn; xs[r][c4 + 1] = v.y * dn;
        xs[r][c4 + 2] = v.z * dn; xs[r][c4 + 3] = v.w * dn;
    }
    __syncthreads();

    int ng = tid & 31;
    int cg = tid >> 5;
    float acc[4][5];
#pragma unroll
    for (int i = 0; i < 4; ++i)
#pragma unroll
        for (int j = 0; j < 5; ++j) acc[i][j] = 0.f;

#pragma unroll 4
    for (int k = 0; k < FDIM; ++k) {
        float xv[4], wv[5];
#pragma unroll
        for (int i = 0; i < 4; ++i) xv[i] = xs[ng + 32 * i][k];
#pragma unroll
        for (int j = 0; j < 5; ++j) wv[j] = Wl[(cg * 5 + j) * 65 + k];
#pragma unroll
        for (int i = 0; i < 4; ++i)
#pragma unroll
            for (int j = 0; j < 5; ++j)
                acc[i][j] = fmaf(xv[i], wv[j], acc[i][j]);
    }
    __syncthreads();

    unsigned short* ps = (unsigned short*)xs;    // [PTILE][64] u16 staging
#pragma unroll
    for (int i = 0; i < 4; ++i) {
        int r = ng + 32 * i;
#pragma unroll
        for (int j = 0; j < 5; ++j)
            ps[r * 64 + cg * 5 + j] = f2bf(acc[i][j]);
    }
    __syncthreads();
    const unsigned int* pu = (const unsigned int*)ps;  // [PTILE][32] u32
    for (int idx = tid; idx < PTILE * 16; idx += 256) {
        int r = idx >> 4, u = idx & 15;
        int n = n0 + r;
        if (n < N) pA[n * 16 + u] = pu[r * 32 + u];
    }
    for (int idx = tid; idx < PTILE * 4; idx += 256) {
        int r = idx >> 2, u = idx & 3;
        int n = n0 + r;
        if (n < N) pB[n * 4 + u] = pu[r * 32 + 16 + u];
    }
}

// ---------------- hop 1: 4-lane-group gather-sum over split planes ---------
// 16 nodes per wave; lane t loads uint4 of plane A (classes 8t..8t+7);
// lane 0 additionally loads plane B's uint4 (classes 32..39).
// Predicated 4-deep batches: 64 rows in flight per wave.

__global__ __launch_bounds__(256) void k_hop1(const int* __restrict__ row_ptr,
                                              const int* __restrict__ csr_src,
                                              const float* __restrict__ dinv,
                                              const uint4* __restrict__ pA4,
                                              const uint4* __restrict__ pB4,
                                              uint4* __restrict__ yA4,
                                              uint4* __restrict__ yB4,
                                              int N) {
    int g = threadIdx.x >> 2;   // group 0..63 (node within block)
    int t = threadIdx.x & 3;    // uint4 slot within plane-A row
    int node = blockIdx.x * 64 + g;
    if (node >= N) return;
    int beg = row_ptr[node], end = row_ptr[node + 1];

    float a[8], bb[8];
#pragma unroll
    for (int j = 0; j < 8; ++j) { a[j] = 0.f; bb[j] = 0.f; }

    for (int e0 = beg; e0 < end; e0 += 4) {
        int si[4]; uint4 vA[4], vB[4];
#pragma unroll
        for (int k = 0; k < 4; ++k) {
            int idx = e0 + k;
            si[k] = (idx < end) ? csr_src[idx] : -1;
        }
#pragma unroll
        for (int k = 0; k < 4; ++k)
            if (si[k] >= 0) vA[k] = pA4[si[k] * 4 + t];
#pragma unroll
        for (int k = 0; k < 4; ++k)
            if (si[k] >= 0 && t == 0) vB[k] = pB4[si[k]];
#pragma unroll
        for (int k = 0; k < 4; ++k)
            if (si[k] >= 0) {
                a[0] += bf_lo(vA[k].x); a[1] += bf_hi(vA[k].x);
                a[2] += bf_lo(vA[k].y); a[3] += bf_hi(vA[k].y);
                a[4] += bf_lo(vA[k].z); a[5] += bf_hi(vA[k].z);
                a[6] += bf_lo(vA[k].w); a[7] += bf_hi(vA[k].w);
            }
#pragma unroll
        for (int k = 0; k < 4; ++k)
            if (si[k] >= 0 && t == 0) {
                bb[0] += bf_lo(vB[k].x); bb[1] += bf_hi(vB[k].x);
                bb[2] += bf_lo(vB[k].y); bb[3] += bf_hi(vB[k].y);
                bb[4] += bf_lo(vB[k].z); bb[5] += bf_hi(vB[k].z);
                bb[6] += bf_lo(vB[k].w); bb[7] += bf_hi(vB[k].w);
            }
    }
    float dn = dinv[node], sc = dn * dn;
    yA4[node * 4 + t] = make_uint4(bfpack(a[0] * sc, a[1] * sc),
                                   bfpack(a[2] * sc, a[3] * sc),
                                   bfpack(a[4] * sc, a[5] * sc),
                                   bfpack(a[6] * sc, a[7] * sc));
    if (t == 0)
        yB4[node] = make_uint4(bfpack(bb[0] * sc, bb[1] * sc),
                               bfpack(bb[2] * sc, bb[3] * sc),
                               bfpack(bb[4] * sc, bb[5] * sc),
                               bfpack(bb[6] * sc, bb[7] * sc));
}

// ---------------- hop 2: same gather + bias + log_softmax ------------------
// lane t holds classes 8t..8t+7; lane 0 also 32..39; reduce over 4 lanes.

__global__ __launch_bounds__(256) void k_hop2_lsm(const int* __restrict__ row_ptr,
                                                  const int* __restrict__ csr_src,
                                                  const float* __restrict__ dinv,
                                                  const uint4* __restrict__ pA4,
                                                  const uint4* __restrict__ pB4,
                                                  const float* __restrict__ bias,
                                                  float* __restrict__ out,
                                                  int N, int C) {
    __shared__ float bl[64];
    int tid = threadIdx.x;
    if (tid < 64) bl[tid] = (tid < C) ? bias[tid] : 0.f;
    __syncthreads();

    int g = tid >> 2;
    int t = tid & 3;
    int node = blockIdx.x * 64 + g;
    if (node >= N) return;
    int beg = row_ptr[node], end = row_ptr[node + 1];

    float a[8], bb[8];
#pragma unroll
    for (int j = 0; j < 8; ++j) { a[j] = 0.f; bb[j] = 0.f; }

    for (int e0 = beg; e0 < end; e0 += 4) {
        int si[4]; uint4 vA[4], vB[4];
#pragma unroll
        for (int k = 0; k < 4; ++k) {
            int idx = e0 + k;
            si[k] = (idx < end) ? csr_src[idx] : -1;
        }
#pragma unroll
        for (int k = 0; k < 4; ++k)
            if (si[k] >= 0) vA[k] = pA4[si[k] * 4 + t];
#pragma unroll
        for (int k = 0; k < 4; ++k)
            if (si[k] >= 0 && t == 0) vB[k] = pB4[si[k]];
#pragma unroll
        for (int k = 0; k < 4; ++k)
            if (si[k] >= 0) {
                a[0] += bf_lo(vA[k].x); a[1] += bf_hi(vA[k].x);
                a[2] += bf_lo(vA[k].y); a[3] += bf_hi(vA[k].y);
                a[4] += bf_lo(vA[k].z); a[5] += bf_hi(vA[k].z);
                a[6] += bf_lo(vA[k].w); a[7] += bf_hi(vA[k].w);
            }
#pragma unroll
        for (int k = 0; k < 4; ++k)
            if (si[k] >= 0 && t == 0) {
                bb[0] += bf_lo(vB[k].x); bb[1] += bf_hi(vB[k].x);
                bb[2] += bf_lo(vB[k].y); bb[3] += bf_hi(vB[k].y);
                bb[4] += bf_lo(vB[k].z); bb[5] += bf_hi(vB[k].z);
                bb[6] += bf_lo(vB[k].w); bb[7] += bf_hi(vB[k].w);
            }
    }

    float dn = dinv[node];
    int c0 = 8 * t;
    float l[8], lb[8];
#pragma unroll
    for (int j = 0; j < 8; ++j) l[j] = fmaf(a[j], dn, bl[c0 + j]);
    float m = l[0];
#pragma unroll
    for (int j = 1; j < 8; ++j) m = fmaxf(m, l[j]);
    if (t == 0) {
#pragma unroll
        for (int j = 0; j < 8; ++j) {
            lb[j] = fmaf(bb[j], dn, bl[32 + j]);
            m = fmaxf(m, lb[j]);
        }
    }
    m = fmaxf(m, __shfl_xor(m, 1));
    m = fmaxf(m, __shfl_xor(m, 2));

    float s = 0.f;
#pragma unroll
    for (int j = 0; j < 8; ++j) s += expf(l[j] - m);
    if (t == 0) {
#pragma unroll
        for (int j = 0; j < 8; ++j) s += expf(lb[j] - m);
    }
    s += __shfl_xor(s, 1);
    s += __shfl_xor(s, 2);
    float ls = m + logf(s);

    float* op = out + (size_t)node * C;
    *(float4*)(op + c0)     = make_float4(l[0] - ls, l[1] - ls, l[2] - ls, l[3] - ls);
    *(float4*)(op + c0 + 4) = make_float4(l[4] - ls, l[5] - ls, l[6] - ls, l[7] - ls);
    if (t == 0) {
        *(float4*)(op + 32) = make_float4(lb[0] - ls, lb[1] - ls, lb[2] - ls, lb[3] - ls);
        *(float4*)(op + 36) = make_float4(lb[4] - ls, lb[5] - ls, lb[6] - ls, lb[7] - ls);
    }
}

// ---------------- launch ----------------

extern "C" void kernel_launch(void* const* d_in, const int* in_sizes, int n_in,
                              void* d_out, int out_size, void* d_ws, size_t ws_size,
                              hipStream_t stream) {
    const float* x  = (const float*)d_in[0];
    const int*   ei = (const int*)d_in[1];
    const float* W  = (const float*)d_in[2];
    const float* b  = (const float*)d_in[3];
    float* out = (float*)d_out;

    const int C = in_sizes[3];              // 40
    const int F = in_sizes[2] / C;          // 64
    const int N = in_sizes[0] / F;          // 100000
    const int E = in_sizes[1] / 2;          // 1200000
    (void)F;

    const int* src = ei;
    const int* dst = ei + E;
    const int T  = E + N;                   // CSR entries incl self-loops
    const int NB = (N + NPB - 1) / NPB;     // buckets (391)

    // ws layout, each segment 256B-aligned
    char* w8 = (char*)d_ws;
    auto alloc = [&](size_t bytes) {
        char* p = w8;
        w8 += (bytes + 255) & ~(size_t)255;
        return p;
    };
    int*   bcnt    = (int*)  alloc((size_t)NB * 4);
    int*   cbase   = (int*)  alloc((size_t)NB * 4);
    int*   row_ptr = (int*)  alloc((size_t)(N + 1) * 4);
    float* dinv    = (float*)alloc((size_t)N * 4);
    unsigned int* bin2 = (unsigned int*)alloc((size_t)NB * CAP2B * 4); // 5.4 MB
    int*   csr_src = (int*)  alloc((size_t)T * 4);                     // 5.2 MB
    unsigned int* pA = (unsigned int*)alloc((size_t)N * 16 * 4);       // 6.4 MB
    unsigned int* pB = (unsigned int*)alloc((size_t)N * 4 * 4);        // 1.6 MB
    unsigned int* yA = (unsigned int*)alloc((size_t)N * 16 * 4);       // 6.4 MB
    unsigned int* yB = (unsigned int*)alloc((size_t)N * 4 * 4);        // 1.6 MB

    const int B = 256;
    const int NT = (E + TILE2 - 1) / TILE2;  // 586 binning tiles

    k_zero <<<(NB + B - 1) / B, B, 0, stream>>>(bcnt, NB);
    k_binD <<<NT, B, 0, stream>>>(src, dst, bcnt, bin2, E, NB);
    k_bscan<<<1, 512, 0, stream>>>(bcnt, cbase, row_ptr, NB, N, T);
    k_build<<<NB, B, 0, stream>>>(bcnt, cbase, bin2, row_ptr, dinv, csr_src, N);

    k_proj <<<(N + PTILE - 1) / PTILE, B, 0, stream>>>(x, W, dinv, pA, pB, N, C);

    k_hop1 <<<(N + 63) / 64, B, 0, stream>>>(row_ptr, csr_src, dinv,
                                             (const uint4*)pA, (const uint4*)pB,
                                             (uint4*)yA, (uint4*)yB, N);

    k_hop2_lsm<<<(N + 63) / 64, B, 0, stream>>>(row_ptr, csr_src, dinv,
                                                (const uint4*)yA, (const uint4*)yB,
                                                b, out, N, C);
}

// Round 21
// 130.141 us; speedup vs baseline: 1.0119x; 1.0119x over previous
//
#include <hip/hip_runtime.h>
#include <math.h>

#define FDIM 64    // input feature dim
#define NPB  256   // nodes per bucket (bucket = dst >> 8)
#define CAP2B 3456 // entries per bucket segment (mean 3069, +7 sigma)
#define NBMAX 400
#define TILE2 2048
#define EPT2 8     // TILE2 / 256
#define PTILE 128  // nodes per k_proj block

// ---------------- helpers ----------------

__device__ inline unsigned short f2bf(float f) {
    unsigned int u = __float_as_uint(f);
    unsigned int r = (u + 0x7fffu + ((u >> 16) & 1u)) >> 16;  // RNE
    return (unsigned short)r;
}
__device__ inline float bf_lo(unsigned int v) { return __uint_as_float(v << 16); }
__device__ inline float bf_hi(unsigned int v) { return __uint_as_float(v & 0xffff0000u); }
__device__ inline unsigned int bfpack(float a, float b) {
    return (unsigned int)f2bf(a) | ((unsigned int)f2bf(b) << 16);
}

__global__ __launch_bounds__(256) void k_zero(int* __restrict__ p, int n) {
    int i = blockIdx.x * 256 + threadIdx.x;
    if (i < n) p[i] = 0;
}

// ---------------- direct binning: edges -> 391 buckets, one pass -----------

__global__ __launch_bounds__(256) void k_binD(const int* __restrict__ src,
                                              const int* __restrict__ dst,
                                              int* __restrict__ bcnt,
                                              unsigned int* __restrict__ bin2,
                                              int E, int NB) {
    __shared__ int hb[NBMAX];   // histogram, then global base
    __shared__ int hc[NBMAX];   // rank cursor
    int tid = threadIdx.x;
    int base = blockIdx.x * TILE2;
    for (int i = tid; i < NB; i += 256) { hb[i] = 0; hc[i] = 0; }
    __syncthreads();
    unsigned int ent[EPT2]; int bk[EPT2];
#pragma unroll
    for (int k = 0; k < EPT2; ++k) {
        int i = base + k * 256 + tid;
        if (i < E) {
            int s = src[i], d = dst[i];
            bk[k] = d >> 8;
            ent[k] = ((unsigned int)s << 8) | (unsigned int)(d & 255);
            atomicAdd(&hb[bk[k]], 1);
        } else bk[k] = -1;
    }
    __syncthreads();
    for (int i = tid; i < NB; i += 256) {
        int c = hb[i];
        hb[i] = (c > 0) ? atomicAdd(&bcnt[i], c) : 0;
    }
    __syncthreads();
#pragma unroll
    for (int k = 0; k < EPT2; ++k) if (bk[k] >= 0) {
        int b = bk[k];
        int pos = hb[b] + atomicAdd(&hc[b], 1);
        if (pos < CAP2B) bin2[(size_t)b * CAP2B + pos] = ent[k];
    }
}

// per bucket: histogram (init 1 = self) + scan -> region via global cursor,
// writes row_info {beg,end} + dinv + src-only CSR entries (no bscan needed:
// CSR regions may be in any bucket order, rows contiguous within a bucket)
__global__ __launch_bounds__(256) void k_build(const int* __restrict__ bcnt,
                                               int* __restrict__ cursor,
                                               const unsigned int* __restrict__ bin2,
                                               int2* __restrict__ row_info,
                                               float* __restrict__ dinv,
                                               int* __restrict__ csr_src, int N) {
    __shared__ int lcnt[256];
    __shared__ int lscan[256];
    __shared__ int lbase[256];
    __shared__ int lcur[256];
    __shared__ int base_s;
    int b = blockIdx.x, tid = threadIdx.x;
    int node = (b << 8) + tid;
    lcnt[tid] = (node < N) ? 1 : 0;          // self entry
    __syncthreads();
    int M = min(bcnt[b], CAP2B);
    const unsigned int* seg = bin2 + (size_t)b * CAP2B;
    for (int i = tid; i < M; i += 256)
        atomicAdd(&lcnt[seg[i] & 255u], 1);
    __syncthreads();
    int v = lcnt[tid];
    lscan[tid] = v;
    __syncthreads();
    int val = v;
#pragma unroll
    for (int off = 1; off < 256; off <<= 1) {
        int o = (tid >= off) ? lscan[tid - off] : 0;
        __syncthreads();
        val += o;
        lscan[tid] = val;
        __syncthreads();
    }
    if (tid == 255) base_s = atomicAdd(cursor, val);  // val = bucket total
    __syncthreads();
    int base = base_s + (val - v);           // exclusive local offset
    if (node < N) {
        row_info[node] = make_int2(base, base + v);
        dinv[node] = rsqrtf((float)v);       // count includes self entry
        csr_src[base] = node;                // self entry at slot 0
    }
    lbase[tid] = base;
    lcur[tid] = 1;                           // slot 0 taken by self
    __syncthreads();
    for (int i = tid; i < M; i += 256) {
        unsigned int en = seg[i];
        int dl = (int)(en & 255u);
        int pos = lbase[dl] + atomicAdd(&lcur[dl], 1);
        csr_src[pos] = (int)(en >> 8);
    }
}

// ---------------- projection: p''[n][c] = dinv[n]*dot(x[n], W[c]) ----------
// register-blocked tiled GEMM: 128-node tile, 4 nodes x 5 classes / thread

__global__ __launch_bounds__(256) void k_proj(const float* __restrict__ x,
                                              const float* __restrict__ W,
                                              const float* __restrict__ dinv,
                                              unsigned short* __restrict__ p16,
                                              int N, int C) {
    __shared__ float xs[PTILE][65];
    __shared__ float Wl[40 * 65];
    int tid = threadIdx.x;
    int n0 = blockIdx.x * PTILE;

    for (int i = tid; i < 40 * 64; i += 256) {
        int c = i >> 6, f = i & 63;
        Wl[c * 65 + f] = W[i];
    }
    for (int idx = tid; idx < PTILE * 16; idx += 256) {
        int r = idx >> 4, c4 = (idx & 15) << 2;
        int n = n0 + r;
        float4 v = make_float4(0.f, 0.f, 0.f, 0.f);
        float dn = 0.f;
        if (n < N) {
            v = *(const float4*)&x[(size_t)n * FDIM + c4];
            dn = dinv[n];
        }
        xs[r][c4 + 0] = v.x * dn; xs[r][c4 + 1] = v.y * dn;
        xs[r][c4 + 2] = v.z * dn; xs[r][c4 + 3] = v.w * dn;
    }
    __syncthreads();

    int ng = tid & 31;
    int cg = tid >> 5;
    float acc[4][5];
#pragma unroll
    for (int i = 0; i < 4; ++i)
#pragma unroll
        for (int j = 0; j < 5; ++j) acc[i][j] = 0.f;

#pragma unroll 4
    for (int k = 0; k < FDIM; ++k) {
        float xv[4], wv[5];
#pragma unroll
        for (int i = 0; i < 4; ++i) xv[i] = xs[ng + 32 * i][k];
#pragma unroll
        for (int j = 0; j < 5; ++j) wv[j] = Wl[(cg * 5 + j) * 65 + k];
#pragma unroll
        for (int i = 0; i < 4; ++i)
#pragma unroll
            for (int j = 0; j < 5; ++j)
                acc[i][j] = fmaf(xv[i], wv[j], acc[i][j]);
    }
    __syncthreads();

    unsigned short* ps = (unsigned short*)xs;    // [PTILE][64] u16
#pragma unroll
    for (int i = 0; i < 4; ++i) {
        int r = ng + 32 * i;
#pragma unroll
        for (int j = 0; j < 5; ++j)
            ps[r * 64 + cg * 5 + j] = f2bf(acc[i][j]);
    }
    for (int idx = tid; idx < PTILE * 24; idx += 256) {
        int r = idx / 24, c = 40 + idx % 24;
        ps[r * 64 + c] = 0;
    }
    __syncthreads();
    const unsigned int* pu = (const unsigned int*)ps;
    unsigned int* po = (unsigned int*)p16;
    for (int idx = tid; idx < PTILE * 32; idx += 256) {
        int r = idx >> 5;
        int n = n0 + r;
        if (n < N) po[(size_t)n * 32 + (idx & 31)] = pu[idx];
    }
}

// ---------------- hop 1: 8-lane-group gather-sum, rescale by dinv^2 --------
// 8 nodes per wave; lane t of a group loads the uint4 slice [16B] of each
// gathered 128B row -> lanes partition columns, no cross-lane reduction.

__global__ __launch_bounds__(256) void k_hop1(const int2* __restrict__ row_info,
                                              const int* __restrict__ csr_src,
                                              const float* __restrict__ dinv,
                                              const uint4* __restrict__ pin4,
                                              uint4* __restrict__ yout4,
                                              int N) {
    int g = threadIdx.x >> 3;   // group 0..31 (node within block)
    int t = threadIdx.x & 7;    // uint4 slot within row
    int node = blockIdx.x * 32 + g;
    if (node >= N) return;
    int2 ri = row_info[node];
    int beg = ri.x, end = ri.y;

    float a0 = 0.f, a1 = 0.f, a2 = 0.f, a3 = 0.f;
    float a4 = 0.f, a5 = 0.f, a6 = 0.f, a7 = 0.f;
    for (int e0 = beg; e0 < end; e0 += 4) {
        int si[4]; uint4 vs[4];
#pragma unroll
        for (int k = 0; k < 4; ++k) {
            int idx = e0 + k;
            si[k] = (idx < end) ? csr_src[idx] : -1;
        }
#pragma unroll
        for (int k = 0; k < 4; ++k)
            if (si[k] >= 0) vs[k] = pin4[si[k] * 8 + t];
#pragma unroll
        for (int k = 0; k < 4; ++k)
            if (si[k] >= 0) {
                a0 += bf_lo(vs[k].x); a1 += bf_hi(vs[k].x);
                a2 += bf_lo(vs[k].y); a3 += bf_hi(vs[k].y);
                a4 += bf_lo(vs[k].z); a5 += bf_hi(vs[k].z);
                a6 += bf_lo(vs[k].w); a7 += bf_hi(vs[k].w);
            }
    }
    float dn = dinv[node], sc = dn * dn;
    yout4[node * 8 + t] = make_uint4(bfpack(a0 * sc, a1 * sc),
                                     bfpack(a2 * sc, a3 * sc),
                                     bfpack(a4 * sc, a5 * sc),
                                     bfpack(a6 * sc, a7 * sc));
}

// ---------------- hop 2: same gather + bias + log_softmax ------------------
// lane t holds classes 8t..8t+7 (valid t<5 for C=40); softmax reduces over
// the 8-lane group via shfl_xor 1/2/4 (stays in group).

__global__ __launch_bounds__(256) void k_hop2_lsm(const int2* __restrict__ row_info,
                                                  const int* __restrict__ csr_src,
                                                  const float* __restrict__ dinv,
                                                  const uint4* __restrict__ pin4,
                                                  const float* __restrict__ bias,
                                                  float* __restrict__ out,
                                                  int N, int C) {
    __shared__ float bl[64];
    int tid = threadIdx.x;
    if (tid < 64) bl[tid] = (tid < C) ? bias[tid] : 0.f;
    __syncthreads();

    int g = tid >> 3;
    int t = tid & 7;
    int node = blockIdx.x * 32 + g;
    if (node >= N) return;
    int2 ri = row_info[node];
    int beg = ri.x, end = ri.y;

    float a[8];
#pragma unroll
    for (int j = 0; j < 8; ++j) a[j] = 0.f;
    for (int e0 = beg; e0 < end; e0 += 4) {
        int si[4]; uint4 vs[4];
#pragma unroll
        for (int k = 0; k < 4; ++k) {
            int idx = e0 + k;
            si[k] = (idx < end) ? csr_src[idx] : -1;
        }
#pragma unroll
        for (int k = 0; k < 4; ++k)
            if (si[k] >= 0) vs[k] = pin4[si[k] * 8 + t];
#pragma unroll
        for (int k = 0; k < 4; ++k)
            if (si[k] >= 0) {
                a[0] += bf_lo(vs[k].x); a[1] += bf_hi(vs[k].x);
                a[2] += bf_lo(vs[k].y); a[3] += bf_hi(vs[k].y);
                a[4] += bf_lo(vs[k].z); a[5] += bf_hi(vs[k].z);
                a[6] += bf_lo(vs[k].w); a[7] += bf_hi(vs[k].w);
            }
    }

    float dn = dinv[node];
    int c0 = 8 * t;
    bool valid = (c0 < C);      // C=40: t<5
    float l[8];
#pragma unroll
    for (int j = 0; j < 8; ++j)
        l[j] = valid ? fmaf(a[j], dn, bl[c0 + j]) : -INFINITY;

    float m = l[0];
#pragma unroll
    for (int j = 1; j < 8; ++j) m = fmaxf(m, l[j]);
    m = fmaxf(m, __shfl_xor(m, 1));
    m = fmaxf(m, __shfl_xor(m, 2));
    m = fmaxf(m, __shfl_xor(m, 4));

    float s = 0.f;
    if (valid) {
#pragma unroll
        for (int j = 0; j < 8; ++j) s += expf(l[j] - m);
    }
    s += __shfl_xor(s, 1);
    s += __shfl_xor(s, 2);
    s += __shfl_xor(s, 4);
    float ls = m + logf(s);

    if (valid) {
        float* op = out + (size_t)node * C + c0;
        float4 r0 = make_float4(l[0] - ls, l[1] - ls, l[2] - ls, l[3] - ls);
        float4 r1 = make_float4(l[4] - ls, l[5] - ls, l[6] - ls, l[7] - ls);
        *(float4*)op = r0;
        *(float4*)(op + 4) = r1;
    }
}

// ---------------- launch ----------------

extern "C" void kernel_launch(void* const* d_in, const int* in_sizes, int n_in,
                              void* d_out, int out_size, void* d_ws, size_t ws_size,
                              hipStream_t stream) {
    const float* x  = (const float*)d_in[0];
    const int*   ei = (const int*)d_in[1];
    const float* W  = (const float*)d_in[2];
    const float* b  = (const float*)d_in[3];
    float* out = (float*)d_out;

    const int C = in_sizes[3];              // 40
    const int F = in_sizes[2] / C;          // 64
    const int N = in_sizes[0] / F;          // 100000
    const int E = in_sizes[1] / 2;          // 1200000
    (void)F;

    const int* src = ei;
    const int* dst = ei + E;
    const int NB = (N + NPB - 1) / NPB;     // buckets (391)

    // ws layout, each segment 256B-aligned
    char* w8 = (char*)d_ws;
    auto alloc = [&](size_t bytes) {
        char* p = w8;
        w8 += (bytes + 255) & ~(size_t)255;
        return p;
    };
    int*   bcnt    = (int*)  alloc((size_t)(NB + 1) * 4);  // + cursor
    int2*  row_info= (int2*) alloc((size_t)N * 8);
    float* dinv    = (float*)alloc((size_t)N * 4);
    unsigned int* bin2 = (unsigned int*)alloc((size_t)NB * CAP2B * 4); // 5.4 MB
    int*   csr_src = (int*)  alloc((size_t)(E + N) * 4);               // 5.2 MB
    unsigned short* p16 = (unsigned short*)alloc((size_t)N * 64 * 2);
    uint4* y16     = (uint4*)alloc((size_t)N * 8 * 16);

    int* cursor = bcnt + NB;

    const int B = 256;
    const int NT = (E + TILE2 - 1) / TILE2;  // 586 binning tiles

    k_zero <<<(NB + 1 + B - 1) / B, B, 0, stream>>>(bcnt, NB + 1);
    k_binD <<<NT, B, 0, stream>>>(src, dst, bcnt, bin2, E, NB);
    k_build<<<NB, B, 0, stream>>>(bcnt, cursor, bin2, row_info, dinv, csr_src, N);

    k_proj <<<(N + PTILE - 1) / PTILE, B, 0, stream>>>(x, W, dinv, p16, N, C);

    k_hop1 <<<(N + 31) / 32, B, 0, stream>>>(row_info, csr_src, dinv,
                                             (const uint4*)p16, y16, N);

    k_hop2_lsm<<<(N + 31) / 32, B, 0, stream>>>(row_info, csr_src, dinv,
                                                (const uint4*)y16, b, out, N, C);
}